// Round 11
// baseline (292.457 us; speedup 1.0000x reference)
//
#include <hip/hip_runtime.h>
#include <hip/hip_fp16.h>

#define D 64
#define NPW 8         // nodes per wave
#define WPB 16        // waves per block (1024 threads)
#define IDXCAP 192    // per-wave LDS staged-index capacity (avg batch = 128, +5.6 sigma)
#define NCH 512       // pass-1/2 chunks (grid)
#define MAXB 512      // max coarse buckets
#define RMAX 20       // p3 register-staged edges per thread

typedef _Float16 f16;
typedef _Float16 f16x8 __attribute__((ext_vector_type(8)));
typedef float f32x4 __attribute__((ext_vector_type(4)));

__device__ __forceinline__ float4 h4_to_f4(uint2 u) {
    float2 fa = __half22float2(__builtin_bit_cast(__half2, u.x));
    float2 fb = __half22float2(__builtin_bit_cast(__half2, u.y));
    return make_float4(fa.x, fa.y, fb.x, fb.y);
}

// ================= two-level histogram CSR build (zero global atomics) =================
// mat is bucket-major: mat[b * NCH + k]

__global__ __launch_bounds__(256) void p1_count_convert(
        const int* __restrict__ dst, int E, int chunk, int* __restrict__ mat, int bshift,
        const float* __restrict__ x, f16* __restrict__ xh, int n4) {
    __shared__ int h[MAXB];
    for (int i = threadIdx.x; i < MAXB; i += 256) h[i] = 0;
    __syncthreads();
    int k = blockIdx.x;
    int e0 = k * chunk;
    int e1 = min(E, e0 + chunk);
    for (int e = e0 + threadIdx.x; e < e1; e += 256)
        atomicAdd(&h[dst[e] >> bshift], 1);
    __syncthreads();
    for (int b = threadIdx.x; b < MAXB; b += 256)
        mat[b * NCH + k] = h[b];
    int t = blockIdx.x * 256 + threadIdx.x;
    int stride = gridDim.x * 256;
    for (int i = t; i < n4; i += stride) {
        float4 v = ((const float4*)x)[i];
        uint2 o;
        o.x = __builtin_bit_cast(unsigned int, __float22half2_rn(make_float2(v.x, v.y)));
        o.y = __builtin_bit_cast(unsigned int, __float22half2_rn(make_float2(v.z, v.w)));
        ((uint2*)xh)[i] = o;
    }
}

__global__ __launch_bounds__(256) void scan_bt(const int* __restrict__ mat, int* __restrict__ tot) {
    __shared__ int sd[256];
    int b = blockIdx.x;
    int s = 0;
    for (int k = threadIdx.x; k < NCH; k += 256) s += mat[b * NCH + k];
    sd[threadIdx.x] = s; __syncthreads();
    for (int off = 128; off > 0; off >>= 1) {
        if (threadIdx.x < off) sd[threadIdx.x] += sd[threadIdx.x + off];
        __syncthreads();
    }
    if (threadIdx.x == 0) tot[b] = sd[0];
}

__global__ __launch_bounds__(512) void scan_tot(const int* __restrict__ tot, int* __restrict__ bucketBase,
                                                int* __restrict__ rowptr, int nbuck, int N, int E) {
    __shared__ int sc[MAXB];
    int t = threadIdx.x;
    int v = (t < nbuck) ? tot[t] : 0;
    sc[t] = v;
    __syncthreads();
    for (int off = 1; off < MAXB; off <<= 1) {
        int add = (t >= off) ? sc[t - off] : 0;
        __syncthreads();
        sc[t] += add;
        __syncthreads();
    }
    if (t < nbuck) bucketBase[t] = sc[t] - v;
    if (t == 0) { bucketBase[nbuck] = E; rowptr[N] = E; }
}

__global__ __launch_bounds__(256) void scan_col(int* __restrict__ mat, const int* __restrict__ bucketBase) {
    __shared__ int part[256];
    int b = blockIdx.x;
    int base = bucketBase[b];
    int t = threadIdx.x;
    int l0 = mat[b * NCH + 2 * t];
    int l1 = mat[b * NCH + 2 * t + 1];
    int lsum = l0 + l1;
    part[t] = lsum;
    __syncthreads();
    for (int off = 1; off < 256; off <<= 1) {
        int add = (t >= off) ? part[t - off] : 0;
        __syncthreads();
        part[t] += add;
        __syncthreads();
    }
    int excl = base + part[t] - lsum;
    mat[b * NCH + 2 * t] = excl;
    mat[b * NCH + 2 * t + 1] = excl + l0;
}

__global__ __launch_bounds__(256) void p2_scatter(
        const int* __restrict__ src, const int* __restrict__ dst, int E, int chunk,
        const int* __restrict__ mat, int bshift, int2* __restrict__ pairs) {
    __shared__ int cur[MAXB];
    int k = blockIdx.x;
    for (int b = threadIdx.x; b < MAXB; b += 256)
        cur[b] = mat[b * NCH + k];
    __syncthreads();
    int e0 = k * chunk;
    int e1 = min(E, e0 + chunk);
    for (int e = e0 + threadIdx.x; e < e1; e += 256) {
        int d = dst[e], s = src[e];
        int pos = atomicAdd(&cur[d >> bshift], 1);   // LDS atomic only
        pairs[pos] = make_int2(d, s);
    }
}

__global__ __launch_bounds__(256) void p3_build(
        const int2* __restrict__ pairs, const int* __restrict__ bucketBase, int bshift,
        int* __restrict__ rowptr, int* __restrict__ csr, int N) {
    __shared__ int hist[1024];
    __shared__ int cur[1024];
    __shared__ int part[256];
    int b = blockIdx.x;
    int npb = 1 << bshift;
    int nb0 = b << bshift;
    int nn = min(N - nb0, npb);
    int e0 = bucketBase[b], e1 = bucketBase[b + 1];
    int cnt = e1 - e0;
    int t = threadIdx.x;
    for (int i = t; i < npb; i += 256) hist[i] = 0;
    __syncthreads();
    bool reg = (cnt <= 256 * RMAX);
    int2 v[RMAX];
    if (reg) {
        #pragma unroll
        for (int r = 0; r < RMAX; ++r) {
            int e = e0 + r * 256 + t;
            if (e < e1) {
                v[r] = pairs[e];
                atomicAdd(&hist[v[r].x - nb0], 1);
            }
        }
    } else {
        for (int e = e0 + t; e < e1; e += 256)
            atomicAdd(&hist[pairs[e].x - nb0], 1);
    }
    __syncthreads();
    int R = (nn + 255) >> 8;
    int base_i = t * R;
    int lsum = 0;
    for (int r = 0; r < R; ++r) { int i = base_i + r; if (i < nn) lsum += hist[i]; }
    part[t] = lsum;
    __syncthreads();
    for (int off = 1; off < 256; off <<= 1) {
        int add = (t >= off) ? part[t - off] : 0;
        __syncthreads();
        part[t] += add;
        __syncthreads();
    }
    int run = e0 + (part[t] - lsum);
    for (int r = 0; r < R; ++r) {
        int i = base_i + r;
        if (i < nn) {
            int hv = hist[i];
            rowptr[nb0 + i] = run;
            cur[i] = run;
            run += hv;
        }
    }
    __syncthreads();
    if (reg) {
        #pragma unroll
        for (int r = 0; r < RMAX; ++r) {
            int e = e0 + r * 256 + t;
            if (e < e1) {
                int pos = atomicAdd(&cur[v[r].x - nb0], 1);   // LDS atomic only
                csr[pos] = v[r].y;
            }
        }
    } else {
        for (int e = e0 + t; e < e1; e += 256) {
            int2 p = pairs[e];
            int pos = atomicAdd(&cur[p.x - nb0], 1);
            csr[pos] = p.y;
        }
    }
}

// ====================== fused SAGE layer: 8 nodes/wave, 32 waves/CU ======================
#define GATHER_BODY(IP)                                                          \
    for (; j + 16 <= deg; j += 16) {                                             \
        int s0 = (IP)[j + r4];                                                   \
        int s1 = (IP)[j + 4 + r4];                                               \
        int s2 = (IP)[j + 8 + r4];                                               \
        int s3 = (IP)[j + 12 + r4];                                              \
        float4 g0 = h4_to_f4(xh2[(size_t)s0 * 16 + f8]);                         \
        float4 g1 = h4_to_f4(xh2[(size_t)s1 * 16 + f8]);                         \
        float4 g2 = h4_to_f4(xh2[(size_t)s2 * 16 + f8]);                         \
        float4 g3 = h4_to_f4(xh2[(size_t)s3 * 16 + f8]);                         \
        acc.x += (g0.x + g1.x) + (g2.x + g3.x);                                  \
        acc.y += (g0.y + g1.y) + (g2.y + g3.y);                                  \
        acc.z += (g0.z + g1.z) + (g2.z + g3.z);                                  \
        acc.w += (g0.w + g1.w) + (g2.w + g3.w);                                  \
    }                                                                            \
    if (j + 8 <= deg) {                                                          \
        int s0 = (IP)[j + r4];                                                   \
        int s1 = (IP)[j + 4 + r4];                                               \
        float4 g0 = h4_to_f4(xh2[(size_t)s0 * 16 + f8]);                         \
        float4 g1 = h4_to_f4(xh2[(size_t)s1 * 16 + f8]);                         \
        acc.x += g0.x + g1.x; acc.y += g0.y + g1.y;                              \
        acc.z += g0.z + g1.z; acc.w += g0.w + g1.w;                              \
        j += 8;                                                                  \
    }                                                                            \
    for (; j < deg; j += 4) {                                                    \
        int jj = j + r4;                                                         \
        if (jj < deg) {                                                          \
            float4 g = h4_to_f4(xh2[(size_t)(IP)[jj] * 16 + f8]);                \
            acc.x += g.x; acc.y += g.y; acc.z += g.z; acc.w += g.w;              \
        }                                                                        \
    }

template<int RELU, int OUT16>
__global__ __launch_bounds__(1024, 8) void sage_mfma(
        const f16* __restrict__ xh, const int* __restrict__ rowptr,
        const int* __restrict__ csr,
        const float* __restrict__ Wl, const float* __restrict__ bias,
        const float* __restrict__ Wr,
        f16* __restrict__ out16, float* __restrict__ out32, int n_nodes) {
    __shared__ __align__(16) f16 sB[16 * 512];       // 16 KB
    __shared__ __align__(16) f16 sA[WPB][16 * 72];   // 36.9 KB (rows 8-15 stay zero)
    __shared__ int sIdx[WPB][IDXCAP];                // 12.3 KB

    // stage B fragments (1024 threads -> one element each)
    for (int u = threadIdx.x; u < 16 * 64; u += blockDim.x) {
        int f = u >> 6;
        int l = u & 63;
        int t = f >> 2, q = f & 3;
        const float* Wsel = (q < 2) ? Wl : Wr;
        int d  = t * 16 + (l & 15);
        int k0 = (q & 1) * 32 + (l >> 4) * 8;
        const float4* wp = (const float4*)(Wsel + d * 64 + k0);
        float4 w0 = wp[0], w1 = wp[1];
        uint4 pk;
        pk.x = __builtin_bit_cast(unsigned int, __float22half2_rn(make_float2(w0.x, w0.y)));
        pk.y = __builtin_bit_cast(unsigned int, __float22half2_rn(make_float2(w0.z, w0.w)));
        pk.z = __builtin_bit_cast(unsigned int, __float22half2_rn(make_float2(w1.x, w1.y)));
        pk.w = __builtin_bit_cast(unsigned int, __float22half2_rn(make_float2(w1.z, w1.w)));
        *(uint4*)&sB[f * 512 + l * 8] = pk;
    }
    // zero sA once (rows 8-15 must be finite for the half-used MFMA tile)
    {
        f16* sAf = &sA[0][0];
        for (int i = threadIdx.x; i < WPB * 16 * 72; i += blockDim.x) sAf[i] = (f16)0.f;
    }
    __syncthreads();

    const int lane = threadIdx.x & 63;
    const int wid  = threadIdx.x >> 6;
    const int r4   = lane >> 4;
    const int f8   = lane & 15;
    f16* myA = &sA[wid][0];
    int* myIdx = &sIdx[wid][0];

    float bias_t[4];
    #pragma unroll
    for (int t = 0; t < 4; ++t) bias_t[t] = bias[t * 16 + f8];

    const int wavesPerBlock = blockDim.x >> 6;
    const int gwave = blockIdx.x * wavesPerBlock + wid;
    const int nwaves = gridDim.x * wavesPerBlock;
    const uint2* __restrict__ xh2 = (const uint2*)xh;

    for (int nb = gwave * NPW; nb < n_nodes; nb += nwaves * NPW) {
        int rpl = 0;
        {
            int ii = nb + lane;
            if (lane < NPW + 1) rpl = rowptr[ii < n_nodes ? ii : n_nodes];
        }
        int rbase = __builtin_amdgcn_readlane(rpl, 0);
        int rend  = __builtin_amdgcn_readlane(rpl, NPW);
        int cnt = rend - rbase;
        bool useLds = (cnt <= IDXCAP);

        if (useLds) {
            for (int c = lane; c < cnt; c += 64)
                myIdx[c] = csr[rbase + c];
        }

        // root-row fragments: rows 0..15 read (rows 8-15 discarded at epilogue)
        int rn = nb + f8; if (rn >= n_nodes) rn = n_nodes - 1;
        const f16x8* rrow = (const f16x8*)(xh + (size_t)rn * 64);
        f16x8 a2 = rrow[r4];
        f16x8 a3 = rrow[4 + r4];

        #pragma unroll 1
        for (int i = 0; i < NPW; ++i) {
            int r0 = __builtin_amdgcn_readlane(rpl, i);
            int r1 = __builtin_amdgcn_readlane(rpl, i + 1);
            int deg = r1 - r0;
            float4 acc = make_float4(0.f, 0.f, 0.f, 0.f);
            int j = 0;
            if (useLds) {
                const int* ip = myIdx + (r0 - rbase);
                GATHER_BODY(ip)
            } else {
                const int* ip = csr + r0;
                GATHER_BODY(ip)
            }
            acc.x += __shfl_xor(acc.x, 16, 64);
            acc.y += __shfl_xor(acc.y, 16, 64);
            acc.z += __shfl_xor(acc.z, 16, 64);
            acc.w += __shfl_xor(acc.w, 16, 64);
            acc.x += __shfl_xor(acc.x, 32, 64);
            acc.y += __shfl_xor(acc.y, 32, 64);
            acc.z += __shfl_xor(acc.z, 32, 64);
            acc.w += __shfl_xor(acc.w, 32, 64);
            float iv = 1.0f / (float)(deg > 0 ? deg : 1);
            if (r4 == (i & 3)) {
                uint2 w;
                w.x = __builtin_bit_cast(unsigned int,
                        __float22half2_rn(make_float2(acc.x * iv, acc.y * iv)));
                w.y = __builtin_bit_cast(unsigned int,
                        __float22half2_rn(make_float2(acc.z * iv, acc.w * iv)));
                *(uint2*)&myA[i * 72 + f8 * 4] = w;
            }
        }

        f16x8 a0 = *(const f16x8*)&myA[f8 * 72 + r4 * 8];
        f16x8 a1 = *(const f16x8*)&myA[f8 * 72 + 32 + r4 * 8];

        #pragma unroll
        for (int t = 0; t < 4; ++t) {
            f32x4 c = {0.f, 0.f, 0.f, 0.f};
            c = __builtin_amdgcn_mfma_f32_16x16x32_f16(a0, *(const f16x8*)&sB[(t*4+0)*512 + lane*8], c, 0, 0, 0);
            c = __builtin_amdgcn_mfma_f32_16x16x32_f16(a1, *(const f16x8*)&sB[(t*4+1)*512 + lane*8], c, 0, 0, 0);
            c = __builtin_amdgcn_mfma_f32_16x16x32_f16(a2, *(const f16x8*)&sB[(t*4+2)*512 + lane*8], c, 0, 0, 0);
            c = __builtin_amdgcn_mfma_f32_16x16x32_f16(a3, *(const f16x8*)&sB[(t*4+3)*512 + lane*8], c, 0, 0, 0);
            #pragma unroll
            for (int rr = 0; rr < 4; ++rr) {
                int row = r4 * 4 + rr;
                if (row < NPW) {                      // rows 8-15 are the dead half-tile
                    int n = nb + row;
                    if (n < n_nodes) {
                        float v = c[rr] + bias_t[t];
                        if (RELU) v = fmaxf(v, 0.f);
                        if (OUT16) out16[(size_t)n * 64 + t * 16 + f8] = (f16)v;
                        else       out32[(size_t)n * 64 + t * 16 + f8] = v;
                    }
                }
            }
        }
    }
}

// =================== fallback CSR build (round-5, atomic rank) ===================

__global__ void count_rank_convert_kernel(const int* __restrict__ dst, int* __restrict__ counts,
                                          int* __restrict__ rank, int E,
                                          const float* __restrict__ x, f16* __restrict__ xh, int n4) {
    int t = blockIdx.x * blockDim.x + threadIdx.x;
    int stride = gridDim.x * blockDim.x;
    int E4 = E >> 2;
    for (int e4 = t; e4 < E4; e4 += stride) {
        int4 d = ((const int4*)dst)[e4];
        int4 rk;
        rk.x = atomicAdd(&counts[d.x], 1);
        rk.y = atomicAdd(&counts[d.y], 1);
        rk.z = atomicAdd(&counts[d.z], 1);
        rk.w = atomicAdd(&counts[d.w], 1);
        ((int4*)rank)[e4] = rk;
    }
    for (int e = (E & ~3) + t; e < E; e += stride)
        rank[e] = atomicAdd(&counts[dst[e]], 1);
    for (int i = t; i < n4; i += stride) {
        float4 v = ((const float4*)x)[i];
        uint2 o;
        o.x = __builtin_bit_cast(unsigned int, __float22half2_rn(make_float2(v.x, v.y)));
        o.y = __builtin_bit_cast(unsigned int, __float22half2_rn(make_float2(v.z, v.w)));
        ((uint2*)xh)[i] = o;
    }
}

__global__ void scan_block_sums(const int* __restrict__ counts, int* __restrict__ partial, int N4) {
    __shared__ int sd[256];
    int idx = blockIdx.x * 256 + threadIdx.x;
    int s = 0;
    if (idx < N4) {
        int4 v = ((const int4*)counts)[idx];
        s = v.x + v.y + v.z + v.w;
    }
    sd[threadIdx.x] = s; __syncthreads();
    for (int off = 128; off > 0; off >>= 1) {
        if (threadIdx.x < off) sd[threadIdx.x] += sd[threadIdx.x + off];
        __syncthreads();
    }
    if (threadIdx.x == 0) partial[blockIdx.x] = sd[0];
}

__global__ void scan_partials(const int* __restrict__ partial, int* __restrict__ pscan,
                              int* __restrict__ rowptr, int NB, int N, int E) {
    if (threadIdx.x == 0 && blockIdx.x == 0) {
        int s = 0;
        for (int i = 0; i < NB; ++i) { pscan[i] = s; s += partial[i]; }
        rowptr[N] = E;
    }
}

__global__ void scan_final(const int* __restrict__ counts, const int* __restrict__ pscan,
                           int* __restrict__ rowptr, int N4) {
    __shared__ int sc[256];
    int idx = blockIdx.x * 256 + threadIdx.x;
    int4 v = make_int4(0, 0, 0, 0);
    if (idx < N4) v = ((const int4*)counts)[idx];
    int msum = v.x + v.y + v.z + v.w;
    sc[threadIdx.x] = msum; __syncthreads();
    for (int off = 1; off < 256; off <<= 1) {
        int add = (threadIdx.x >= (unsigned)off) ? sc[threadIdx.x - off] : 0;
        __syncthreads();
        sc[threadIdx.x] += add;
        __syncthreads();
    }
    int excl = sc[threadIdx.x] - msum + pscan[blockIdx.x];
    if (idx < N4) {
        int4 r;
        r.x = excl;
        r.y = excl + v.x;
        r.z = r.y + v.y;
        r.w = r.z + v.z;
        ((int4*)rowptr)[idx] = r;
    }
}

__global__ void fill_csr2(const int* __restrict__ src, const int* __restrict__ dst,
                          const int* __restrict__ rowptr, const int* __restrict__ rank,
                          int* __restrict__ csr, int E) {
    int t = blockIdx.x * blockDim.x + threadIdx.x;
    int stride = gridDim.x * blockDim.x;
    int E4 = E >> 2;
    for (int e4 = t; e4 < E4; e4 += stride) {
        int4 d = ((const int4*)dst)[e4];
        int4 rk = ((const int4*)rank)[e4];
        int4 s = ((const int4*)src)[e4];
        csr[rowptr[d.x] + rk.x] = s.x;
        csr[rowptr[d.y] + rk.y] = s.y;
        csr[rowptr[d.z] + rk.z] = s.z;
        csr[rowptr[d.w] + rk.w] = s.w;
    }
    for (int e = (E & ~3) + t; e < E; e += stride)
        csr[rowptr[dst[e]] + rank[e]] = src[e];
}

// ============================ launch ============================

extern "C" void kernel_launch(void* const* d_in, const int* in_sizes, int n_in,
                              void* d_out, int out_size, void* d_ws, size_t ws_size,
                              hipStream_t stream) {
    const float* x   = (const float*)d_in[0];
    const int*   ei  = (const int*)d_in[1];
    const float* W1l = (const float*)d_in[2];
    const float* b1  = (const float*)d_in[3];
    const float* W1r = (const float*)d_in[4];
    const float* W2l = (const float*)d_in[5];
    const float* b2  = (const float*)d_in[6];
    const float* W2r = (const float*)d_in[7];
    float* out = (float*)d_out;

    const int N = in_sizes[0] / D;   // 100000
    const int E = in_sizes[1] / 2;   // 1600000
    const int* src = ei;
    const int* dst = ei + E;

    int wavesNeeded = (N + NPW - 1) / NPW;            // 12500
    int blocks = (wavesNeeded + WPB - 1) / WPB;       // 782 (16 waves / 1024 threads per block)

    int bshift = 0;
    while ((1 << bshift) <= 1024 && ((N + (1 << bshift) - 1) >> bshift) > MAXB) ++bshift;
    bool bok = ((1 << bshift) <= 1024) && (((N + (1 << bshift) - 1) >> bshift) <= MAXB);
    int nbuck = bok ? ((N + (1 << bshift) - 1) >> bshift) : 0;

    // ---- preferred: histogram-partition CSR build (parallel scans, reg-staged p3) ----
    {
        size_t off = 0;
        auto alloc = [&](size_t bytes) { size_t r = off; off += (bytes + 511) & ~(size_t)511; return r; };
        size_t o_mat    = alloc((size_t)MAXB * NCH * 4);
        size_t o_tot    = alloc((size_t)MAXB * 4);
        size_t o_bb     = alloc((size_t)(MAXB + 1) * 4);
        size_t o_pairs  = alloc((size_t)E * 8);
        size_t o_rowptr = alloc((size_t)(N + 1) * 4);
        size_t o_csr    = alloc((size_t)E * 4);
        size_t o_xh     = alloc((size_t)N * D * 2);
        size_t o_hh     = alloc((size_t)N * D * 2);

        if (bok && E >= 1 && off <= ws_size) {
            int*  mat    = (int*)((char*)d_ws + o_mat);
            int*  tot    = (int*)((char*)d_ws + o_tot);
            int*  bb     = (int*)((char*)d_ws + o_bb);
            int2* pairs  = (int2*)((char*)d_ws + o_pairs);
            int*  rowptr = (int*)((char*)d_ws + o_rowptr);
            int*  csr    = (int*)((char*)d_ws + o_csr);
            f16*  xh     = (f16*)((char*)d_ws + o_xh);
            f16*  hh     = (f16*)((char*)d_ws + o_hh);

            int chunk = (E + NCH - 1) / NCH;
            p1_count_convert<<<NCH, 256, 0, stream>>>(dst, E, chunk, mat, bshift, x, xh, N * D / 4);
            scan_bt<<<nbuck, 256, 0, stream>>>(mat, tot);
            scan_tot<<<1, 512, 0, stream>>>(tot, bb, rowptr, nbuck, N, E);
            scan_col<<<nbuck, 256, 0, stream>>>(mat, bb);
            p2_scatter<<<NCH, 256, 0, stream>>>(src, dst, E, chunk, mat, bshift, pairs);
            p3_build<<<nbuck, 256, 0, stream>>>(pairs, bb, bshift, rowptr, csr, N);

            sage_mfma<1, 1><<<blocks, 1024, 0, stream>>>(xh, rowptr, csr, W1l, b1, W1r, hh, nullptr, N);
            sage_mfma<0, 0><<<blocks, 1024, 0, stream>>>(hh, rowptr, csr, W2l, b2, W2r, nullptr, out, N);
            return;
        }
    }

    // ---- fallback: round-5 CSR path (atomic rank; needs ~33 MB, proven) ----
    const int N4 = N / 4;
    const int NB = (N4 + 255) / 256;
    size_t off = 0;
    auto alloc = [&](size_t bytes) { size_t r = off; off += (bytes + 511) & ~(size_t)511; return r; };
    size_t f_counts = alloc((size_t)N * 4);
    size_t f_rowptr = alloc((size_t)(N + 1) * 4);
    size_t f_part   = alloc((size_t)NB * 4);
    size_t f_pscan  = alloc((size_t)NB * 4);
    size_t f_csr    = alloc((size_t)E * 4);
    size_t f_xh     = alloc((size_t)N * D * 2);
    size_t f_hh     = alloc((size_t)N * D * 2);

    int* counts  = (int*)((char*)d_ws + f_counts);
    int* rowptr  = (int*)((char*)d_ws + f_rowptr);
    int* partial = (int*)((char*)d_ws + f_part);
    int* pscan   = (int*)((char*)d_ws + f_pscan);
    int* csr     = (int*)((char*)d_ws + f_csr);
    f16* xh      = (f16*)((char*)d_ws + f_xh);
    f16* hh      = (f16*)((char*)d_ws + f_hh);
    int* rank    = (int*)hh;

    hipMemsetAsync(counts, 0, (size_t)N * 4, stream);
    count_rank_convert_kernel<<<2048, 256, 0, stream>>>(dst, counts, rank, E, x, xh, N * D / 4);
    scan_block_sums<<<NB, 256, 0, stream>>>(counts, partial, N4);
    scan_partials<<<1, 64, 0, stream>>>(partial, pscan, rowptr, NB, N, E);
    scan_final<<<NB, 256, 0, stream>>>(counts, pscan, rowptr, N4);
    fill_csr2<<<2048, 256, 0, stream>>>(src, dst, rowptr, rank, csr, E);

    sage_mfma<1, 1><<<blocks, 1024, 0, stream>>>(xh, rowptr, csr, W1l, b1, W1r, hh, nullptr, N);
    sage_mfma<0, 0><<<blocks, 1024, 0, stream>>>(hh, rowptr, csr, W2l, b2, W2r, nullptr, out, N);
}

// Round 12
// 179.070 us; speedup vs baseline: 1.6332x; 1.6332x over previous
//
#include <hip/hip_runtime.h>
#include <hip/hip_fp16.h>

#define D 64
#define IDXCAP 448    // per-wave LDS staged-index capacity (avg batch = 256)
#define NCH 512       // pass-1/2 chunks (grid)
#define MAXB 512      // max coarse buckets
#define RMAX 20       // p3 register-staged edges per thread

typedef _Float16 f16;
typedef _Float16 f16x8 __attribute__((ext_vector_type(8)));
typedef float f32x4 __attribute__((ext_vector_type(4)));

__device__ __forceinline__ float4 h4_to_f4(uint2 u) {
    float2 fa = __half22float2(__builtin_bit_cast(__half2, u.x));
    float2 fb = __half22float2(__builtin_bit_cast(__half2, u.y));
    return make_float4(fa.x, fa.y, fb.x, fb.y);
}

// ================= two-level histogram CSR build (zero global atomics) =================
// mat is bucket-major: mat[b * NCH + k]

__global__ __launch_bounds__(256) void p1_count_convert(
        const int* __restrict__ dst, int E, int chunk, int* __restrict__ mat, int bshift,
        const float* __restrict__ x, f16* __restrict__ xh, int n4) {
    __shared__ int h[MAXB];
    for (int i = threadIdx.x; i < MAXB; i += 256) h[i] = 0;
    __syncthreads();
    int k = blockIdx.x;
    int e0 = k * chunk;
    int e1 = min(E, e0 + chunk);
    for (int e = e0 + threadIdx.x; e < e1; e += 256)
        atomicAdd(&h[dst[e] >> bshift], 1);
    __syncthreads();
    for (int b = threadIdx.x; b < MAXB; b += 256)
        mat[b * NCH + k] = h[b];
    int t = blockIdx.x * 256 + threadIdx.x;
    int stride = gridDim.x * 256;
    for (int i = t; i < n4; i += stride) {
        float4 v = ((const float4*)x)[i];
        uint2 o;
        o.x = __builtin_bit_cast(unsigned int, __float22half2_rn(make_float2(v.x, v.y)));
        o.y = __builtin_bit_cast(unsigned int, __float22half2_rn(make_float2(v.z, v.w)));
        ((uint2*)xh)[i] = o;
    }
}

__global__ __launch_bounds__(256) void scan_bt(const int* __restrict__ mat, int* __restrict__ tot) {
    __shared__ int sd[256];
    int b = blockIdx.x;
    int s = 0;
    for (int k = threadIdx.x; k < NCH; k += 256) s += mat[b * NCH + k];
    sd[threadIdx.x] = s; __syncthreads();
    for (int off = 128; off > 0; off >>= 1) {
        if (threadIdx.x < off) sd[threadIdx.x] += sd[threadIdx.x + off];
        __syncthreads();
    }
    if (threadIdx.x == 0) tot[b] = sd[0];
}

__global__ __launch_bounds__(512) void scan_tot(const int* __restrict__ tot, int* __restrict__ bucketBase,
                                                int* __restrict__ rowptr, int nbuck, int N, int E) {
    __shared__ int sc[MAXB];
    int t = threadIdx.x;
    int v = (t < nbuck) ? tot[t] : 0;
    sc[t] = v;
    __syncthreads();
    for (int off = 1; off < MAXB; off <<= 1) {
        int add = (t >= off) ? sc[t - off] : 0;
        __syncthreads();
        sc[t] += add;
        __syncthreads();
    }
    if (t < nbuck) bucketBase[t] = sc[t] - v;
    if (t == 0) { bucketBase[nbuck] = E; rowptr[N] = E; }
}

__global__ __launch_bounds__(256) void scan_col(int* __restrict__ mat, const int* __restrict__ bucketBase) {
    __shared__ int part[256];
    int b = blockIdx.x;
    int base = bucketBase[b];
    int t = threadIdx.x;
    int l0 = mat[b * NCH + 2 * t];
    int l1 = mat[b * NCH + 2 * t + 1];
    int lsum = l0 + l1;
    part[t] = lsum;
    __syncthreads();
    for (int off = 1; off < 256; off <<= 1) {
        int add = (t >= off) ? part[t - off] : 0;
        __syncthreads();
        part[t] += add;
        __syncthreads();
    }
    int excl = base + part[t] - lsum;
    mat[b * NCH + 2 * t] = excl;
    mat[b * NCH + 2 * t + 1] = excl + l0;
}

__global__ __launch_bounds__(256) void p2_scatter(
        const int* __restrict__ src, const int* __restrict__ dst, int E, int chunk,
        const int* __restrict__ mat, int bshift, int2* __restrict__ pairs) {
    __shared__ int cur[MAXB];
    int k = blockIdx.x;
    for (int b = threadIdx.x; b < MAXB; b += 256)
        cur[b] = mat[b * NCH + k];
    __syncthreads();
    int e0 = k * chunk;
    int e1 = min(E, e0 + chunk);
    for (int e = e0 + threadIdx.x; e < e1; e += 256) {
        int d = dst[e], s = src[e];
        int pos = atomicAdd(&cur[d >> bshift], 1);   // LDS atomic only
        pairs[pos] = make_int2(d, s);
    }
}

__global__ __launch_bounds__(256) void p3_build(
        const int2* __restrict__ pairs, const int* __restrict__ bucketBase, int bshift,
        int* __restrict__ rowptr, int* __restrict__ csr, int N) {
    __shared__ int hist[1024];
    __shared__ int cur[1024];
    __shared__ int part[256];
    int b = blockIdx.x;
    int npb = 1 << bshift;
    int nb0 = b << bshift;
    int nn = min(N - nb0, npb);
    int e0 = bucketBase[b], e1 = bucketBase[b + 1];
    int cnt = e1 - e0;
    int t = threadIdx.x;
    for (int i = t; i < npb; i += 256) hist[i] = 0;
    __syncthreads();
    bool reg = (cnt <= 256 * RMAX);
    int2 v[RMAX];
    if (reg) {
        #pragma unroll
        for (int r = 0; r < RMAX; ++r) {
            int e = e0 + r * 256 + t;
            if (e < e1) {
                v[r] = pairs[e];
                atomicAdd(&hist[v[r].x - nb0], 1);
            }
        }
    } else {
        for (int e = e0 + t; e < e1; e += 256)
            atomicAdd(&hist[pairs[e].x - nb0], 1);
    }
    __syncthreads();
    int R = (nn + 255) >> 8;
    int base_i = t * R;
    int lsum = 0;
    for (int r = 0; r < R; ++r) { int i = base_i + r; if (i < nn) lsum += hist[i]; }
    part[t] = lsum;
    __syncthreads();
    for (int off = 1; off < 256; off <<= 1) {
        int add = (t >= off) ? part[t - off] : 0;
        __syncthreads();
        part[t] += add;
        __syncthreads();
    }
    int run = e0 + (part[t] - lsum);
    for (int r = 0; r < R; ++r) {
        int i = base_i + r;
        if (i < nn) {
            int hv = hist[i];
            rowptr[nb0 + i] = run;
            cur[i] = run;
            run += hv;
        }
    }
    __syncthreads();
    if (reg) {
        #pragma unroll
        for (int r = 0; r < RMAX; ++r) {
            int e = e0 + r * 256 + t;
            if (e < e1) {
                int pos = atomicAdd(&cur[v[r].x - nb0], 1);   // LDS atomic only
                csr[pos] = v[r].y;
            }
        }
    } else {
        for (int e = e0 + t; e < e1; e += 256) {
            int2 p = pairs[e];
            int pos = atomicAdd(&cur[p.x - nb0], 1);
            csr[pos] = p.y;
        }
    }
}

// ====================== fused SAGE layer (round-7/10 form; IDX toggles sIdx staging) ======================
#define GATHER_BODY(IP)                                                          \
    for (; j + 16 <= deg; j += 16) {                                             \
        int s0 = (IP)[j + r4];                                                   \
        int s1 = (IP)[j + 4 + r4];                                               \
        int s2 = (IP)[j + 8 + r4];                                               \
        int s3 = (IP)[j + 12 + r4];                                              \
        float4 g0 = h4_to_f4(xh2[(size_t)s0 * 16 + f8]);                         \
        float4 g1 = h4_to_f4(xh2[(size_t)s1 * 16 + f8]);                         \
        float4 g2 = h4_to_f4(xh2[(size_t)s2 * 16 + f8]);                         \
        float4 g3 = h4_to_f4(xh2[(size_t)s3 * 16 + f8]);                         \
        acc.x += (g0.x + g1.x) + (g2.x + g3.x);                                  \
        acc.y += (g0.y + g1.y) + (g2.y + g3.y);                                  \
        acc.z += (g0.z + g1.z) + (g2.z + g3.z);                                  \
        acc.w += (g0.w + g1.w) + (g2.w + g3.w);                                  \
    }                                                                            \
    if (j + 8 <= deg) {                                                          \
        int s0 = (IP)[j + r4];                                                   \
        int s1 = (IP)[j + 4 + r4];                                               \
        float4 g0 = h4_to_f4(xh2[(size_t)s0 * 16 + f8]);                         \
        float4 g1 = h4_to_f4(xh2[(size_t)s1 * 16 + f8]);                         \
        acc.x += g0.x + g1.x; acc.y += g0.y + g1.y;                              \
        acc.z += g0.z + g1.z; acc.w += g0.w + g1.w;                              \
        j += 8;                                                                  \
    }                                                                            \
    for (; j < deg; j += 4) {                                                    \
        int jj = j + r4;                                                         \
        if (jj < deg) {                                                          \
            float4 g = h4_to_f4(xh2[(size_t)(IP)[jj] * 16 + f8]);                \
            acc.x += g.x; acc.y += g.y; acc.z += g.z; acc.w += g.w;              \
        }                                                                        \
    }

// IDX=1: stage batch indices in LDS (48KB LDS, 3 blocks/CU) — proven 57us config.
// IDX=0: no sIdx (34KB LDS -> 4 blocks/CU, 32 waves); indices read direct from csr.
template<int RELU, int OUT16, int IDX>
__global__ __launch_bounds__(512, 4) void sage_mfma(
        const f16* __restrict__ xh, const int* __restrict__ rowptr,
        const int* __restrict__ csr,
        const float* __restrict__ Wl, const float* __restrict__ bias,
        const float* __restrict__ Wr,
        f16* __restrict__ out16, float* __restrict__ out32, int n_nodes) {
    __shared__ __align__(16) f16 sB[16 * 512];
    __shared__ __align__(16) f16 sA[8][16 * 72];
    __shared__ int sIdx[IDX ? 8 * IDXCAP : 8];

    for (int u = threadIdx.x; u < 16 * 64; u += blockDim.x) {
        int f = u >> 6;
        int l = u & 63;
        int t = f >> 2, q = f & 3;
        const float* Wsel = (q < 2) ? Wl : Wr;
        int d  = t * 16 + (l & 15);
        int k0 = (q & 1) * 32 + (l >> 4) * 8;
        const float4* wp = (const float4*)(Wsel + d * 64 + k0);
        float4 w0 = wp[0], w1 = wp[1];
        uint4 pk;
        pk.x = __builtin_bit_cast(unsigned int, __float22half2_rn(make_float2(w0.x, w0.y)));
        pk.y = __builtin_bit_cast(unsigned int, __float22half2_rn(make_float2(w0.z, w0.w)));
        pk.z = __builtin_bit_cast(unsigned int, __float22half2_rn(make_float2(w1.x, w1.y)));
        pk.w = __builtin_bit_cast(unsigned int, __float22half2_rn(make_float2(w1.z, w1.w)));
        *(uint4*)&sB[f * 512 + l * 8] = pk;
    }
    __syncthreads();

    const int lane = threadIdx.x & 63;
    const int wid  = threadIdx.x >> 6;
    const int r4   = lane >> 4;
    const int f8   = lane & 15;
    f16* myA = &sA[wid][0];
    int* myIdx = IDX ? &sIdx[wid * IDXCAP] : nullptr;

    float bias_t[4];
    #pragma unroll
    for (int t = 0; t < 4; ++t) bias_t[t] = bias[t * 16 + f8];

    const int wavesPerBlock = blockDim.x >> 6;
    const int gwave = blockIdx.x * wavesPerBlock + wid;
    const int nwaves = gridDim.x * wavesPerBlock;
    const uint2* __restrict__ xh2 = (const uint2*)xh;

    for (int nb = gwave * 16; nb < n_nodes; nb += nwaves * 16) {
        int rpl = 0;
        {
            int ii = nb + lane;
            if (lane < 17) rpl = rowptr[ii < n_nodes ? ii : n_nodes];
        }
        int rbase = __builtin_amdgcn_readlane(rpl, 0);
        bool useLds = false;
        if (IDX) {
            int rend = __builtin_amdgcn_readlane(rpl, 16);
            int cnt = rend - rbase;
            useLds = (cnt <= IDXCAP);
            if (useLds) {
                for (int c = lane; c < cnt; c += 64)
                    myIdx[c] = csr[rbase + c];
            }
        }

        int rn = nb + f8; if (rn >= n_nodes) rn = n_nodes - 1;
        const f16x8* rrow = (const f16x8*)(xh + (size_t)rn * 64);
        f16x8 a2 = rrow[r4];
        f16x8 a3 = rrow[4 + r4];

        #pragma unroll 1
        for (int i = 0; i < 16; ++i) {
            int r0 = __builtin_amdgcn_readlane(rpl, i);
            int r1 = __builtin_amdgcn_readlane(rpl, i + 1);
            int deg = r1 - r0;
            float4 acc = make_float4(0.f, 0.f, 0.f, 0.f);
            int j = 0;
            if (IDX && useLds) {
                const int* ip = myIdx + (r0 - rbase);
                GATHER_BODY(ip)
            } else {
                const int* ip = csr + r0;
                GATHER_BODY(ip)
            }
            acc.x += __shfl_xor(acc.x, 16, 64);
            acc.y += __shfl_xor(acc.y, 16, 64);
            acc.z += __shfl_xor(acc.z, 16, 64);
            acc.w += __shfl_xor(acc.w, 16, 64);
            acc.x += __shfl_xor(acc.x, 32, 64);
            acc.y += __shfl_xor(acc.y, 32, 64);
            acc.z += __shfl_xor(acc.z, 32, 64);
            acc.w += __shfl_xor(acc.w, 32, 64);
            float iv = 1.0f / (float)(deg > 0 ? deg : 1);
            if (r4 == (i & 3)) {
                uint2 w;
                w.x = __builtin_bit_cast(unsigned int,
                        __float22half2_rn(make_float2(acc.x * iv, acc.y * iv)));
                w.y = __builtin_bit_cast(unsigned int,
                        __float22half2_rn(make_float2(acc.z * iv, acc.w * iv)));
                *(uint2*)&myA[i * 72 + f8 * 4] = w;
            }
        }

        f16x8 a0 = *(const f16x8*)&myA[f8 * 72 + r4 * 8];
        f16x8 a1 = *(const f16x8*)&myA[f8 * 72 + 32 + r4 * 8];

        #pragma unroll
        for (int t = 0; t < 4; ++t) {
            f32x4 c = {0.f, 0.f, 0.f, 0.f};
            c = __builtin_amdgcn_mfma_f32_16x16x32_f16(a0, *(const f16x8*)&sB[(t*4+0)*512 + lane*8], c, 0, 0, 0);
            c = __builtin_amdgcn_mfma_f32_16x16x32_f16(a1, *(const f16x8*)&sB[(t*4+1)*512 + lane*8], c, 0, 0, 0);
            c = __builtin_amdgcn_mfma_f32_16x16x32_f16(a2, *(const f16x8*)&sB[(t*4+2)*512 + lane*8], c, 0, 0, 0);
            c = __builtin_amdgcn_mfma_f32_16x16x32_f16(a3, *(const f16x8*)&sB[(t*4+3)*512 + lane*8], c, 0, 0, 0);
            #pragma unroll
            for (int rr = 0; rr < 4; ++rr) {
                int n = nb + r4 * 4 + rr;
                if (n < n_nodes) {
                    float v = c[rr] + bias_t[t];
                    if (RELU) v = fmaxf(v, 0.f);
                    if (OUT16) out16[(size_t)n * 64 + t * 16 + f8] = (f16)v;
                    else       out32[(size_t)n * 64 + t * 16 + f8] = v;
                }
            }
        }
    }
}

// =================== fallback CSR build (round-5, atomic rank) ===================

__global__ void count_rank_convert_kernel(const int* __restrict__ dst, int* __restrict__ counts,
                                          int* __restrict__ rank, int E,
                                          const float* __restrict__ x, f16* __restrict__ xh, int n4) {
    int t = blockIdx.x * blockDim.x + threadIdx.x;
    int stride = gridDim.x * blockDim.x;
    int E4 = E >> 2;
    for (int e4 = t; e4 < E4; e4 += stride) {
        int4 d = ((const int4*)dst)[e4];
        int4 rk;
        rk.x = atomicAdd(&counts[d.x], 1);
        rk.y = atomicAdd(&counts[d.y], 1);
        rk.z = atomicAdd(&counts[d.z], 1);
        rk.w = atomicAdd(&counts[d.w], 1);
        ((int4*)rank)[e4] = rk;
    }
    for (int e = (E & ~3) + t; e < E; e += stride)
        rank[e] = atomicAdd(&counts[dst[e]], 1);
    for (int i = t; i < n4; i += stride) {
        float4 v = ((const float4*)x)[i];
        uint2 o;
        o.x = __builtin_bit_cast(unsigned int, __float22half2_rn(make_float2(v.x, v.y)));
        o.y = __builtin_bit_cast(unsigned int, __float22half2_rn(make_float2(v.z, v.w)));
        ((uint2*)xh)[i] = o;
    }
}

__global__ void scan_block_sums(const int* __restrict__ counts, int* __restrict__ partial, int N4) {
    __shared__ int sd[256];
    int idx = blockIdx.x * 256 + threadIdx.x;
    int s = 0;
    if (idx < N4) {
        int4 v = ((const int4*)counts)[idx];
        s = v.x + v.y + v.z + v.w;
    }
    sd[threadIdx.x] = s; __syncthreads();
    for (int off = 128; off > 0; off >>= 1) {
        if (threadIdx.x < off) sd[threadIdx.x] += sd[threadIdx.x + off];
        __syncthreads();
    }
    if (threadIdx.x == 0) partial[blockIdx.x] = sd[0];
}

__global__ void scan_partials(const int* __restrict__ partial, int* __restrict__ pscan,
                              int* __restrict__ rowptr, int NB, int N, int E) {
    if (threadIdx.x == 0 && blockIdx.x == 0) {
        int s = 0;
        for (int i = 0; i < NB; ++i) { pscan[i] = s; s += partial[i]; }
        rowptr[N] = E;
    }
}

__global__ void scan_final(const int* __restrict__ counts, const int* __restrict__ pscan,
                           int* __restrict__ rowptr, int N4) {
    __shared__ int sc[256];
    int idx = blockIdx.x * 256 + threadIdx.x;
    int4 v = make_int4(0, 0, 0, 0);
    if (idx < N4) v = ((const int4*)counts)[idx];
    int msum = v.x + v.y + v.z + v.w;
    sc[threadIdx.x] = msum; __syncthreads();
    for (int off = 1; off < 256; off <<= 1) {
        int add = (threadIdx.x >= (unsigned)off) ? sc[threadIdx.x - off] : 0;
        __syncthreads();
        sc[threadIdx.x] += add;
        __syncthreads();
    }
    int excl = sc[threadIdx.x] - msum + pscan[blockIdx.x];
    if (idx < N4) {
        int4 r;
        r.x = excl;
        r.y = excl + v.x;
        r.z = r.y + v.y;
        r.w = r.z + v.z;
        ((int4*)rowptr)[idx] = r;
    }
}

__global__ void fill_csr2(const int* __restrict__ src, const int* __restrict__ dst,
                          const int* __restrict__ rowptr, const int* __restrict__ rank,
                          int* __restrict__ csr, int E) {
    int t = blockIdx.x * blockDim.x + threadIdx.x;
    int stride = gridDim.x * blockDim.x;
    int E4 = E >> 2;
    for (int e4 = t; e4 < E4; e4 += stride) {
        int4 d = ((const int4*)dst)[e4];
        int4 rk = ((const int4*)rank)[e4];
        int4 s = ((const int4*)src)[e4];
        csr[rowptr[d.x] + rk.x] = s.x;
        csr[rowptr[d.y] + rk.y] = s.y;
        csr[rowptr[d.z] + rk.z] = s.z;
        csr[rowptr[d.w] + rk.w] = s.w;
    }
    for (int e = (E & ~3) + t; e < E; e += stride)
        csr[rowptr[dst[e]] + rank[e]] = src[e];
}

// ============================ launch ============================

extern "C" void kernel_launch(void* const* d_in, const int* in_sizes, int n_in,
                              void* d_out, int out_size, void* d_ws, size_t ws_size,
                              hipStream_t stream) {
    const float* x   = (const float*)d_in[0];
    const int*   ei  = (const int*)d_in[1];
    const float* W1l = (const float*)d_in[2];
    const float* b1  = (const float*)d_in[3];
    const float* W1r = (const float*)d_in[4];
    const float* W2l = (const float*)d_in[5];
    const float* b2  = (const float*)d_in[6];
    const float* W2r = (const float*)d_in[7];
    float* out = (float*)d_out;

    const int N = in_sizes[0] / D;   // 100000
    const int E = in_sizes[1] / 2;   // 1600000
    const int* src = ei;
    const int* dst = ei + E;

    int wavesNeeded = (N + 15) / 16;
    int blocks = (wavesNeeded + 7) / 8;       // 8 waves (512 threads) per block

    int bshift = 0;
    while ((1 << bshift) <= 1024 && ((N + (1 << bshift) - 1) >> bshift) > MAXB) ++bshift;
    bool bok = ((1 << bshift) <= 1024) && (((N + (1 << bshift) - 1) >> bshift) <= MAXB);
    int nbuck = bok ? ((N + (1 << bshift) - 1) >> bshift) : 0;

    // ---- preferred: histogram-partition CSR build (parallel scans, reg-staged p3) ----
    {
        size_t off = 0;
        auto alloc = [&](size_t bytes) { size_t r = off; off += (bytes + 511) & ~(size_t)511; return r; };
        size_t o_mat    = alloc((size_t)MAXB * NCH * 4);
        size_t o_tot    = alloc((size_t)MAXB * 4);
        size_t o_bb     = alloc((size_t)(MAXB + 1) * 4);
        size_t o_pairs  = alloc((size_t)E * 8);
        size_t o_rowptr = alloc((size_t)(N + 1) * 4);
        size_t o_csr    = alloc((size_t)E * 4);
        size_t o_xh     = alloc((size_t)N * D * 2);
        size_t o_hh     = alloc((size_t)N * D * 2);

        if (bok && E >= 1 && off <= ws_size) {
            int*  mat    = (int*)((char*)d_ws + o_mat);
            int*  tot    = (int*)((char*)d_ws + o_tot);
            int*  bb     = (int*)((char*)d_ws + o_bb);
            int2* pairs  = (int2*)((char*)d_ws + o_pairs);
            int*  rowptr = (int*)((char*)d_ws + o_rowptr);
            int*  csr    = (int*)((char*)d_ws + o_csr);
            f16*  xh     = (f16*)((char*)d_ws + o_xh);
            f16*  hh     = (f16*)((char*)d_ws + o_hh);

            int chunk = (E + NCH - 1) / NCH;
            p1_count_convert<<<NCH, 256, 0, stream>>>(dst, E, chunk, mat, bshift, x, xh, N * D / 4);
            scan_bt<<<nbuck, 256, 0, stream>>>(mat, tot);
            scan_tot<<<1, 512, 0, stream>>>(tot, bb, rowptr, nbuck, N, E);
            scan_col<<<nbuck, 256, 0, stream>>>(mat, bb);
            p2_scatter<<<NCH, 256, 0, stream>>>(src, dst, E, chunk, mat, bshift, pairs);
            p3_build<<<nbuck, 256, 0, stream>>>(pairs, bb, bshift, rowptr, csr, N);

            // A/B: layer 1 = proven staged-idx config; layer 2 = high-occupancy no-sIdx variant
            sage_mfma<1, 1, 1><<<blocks, 512, 0, stream>>>(xh, rowptr, csr, W1l, b1, W1r, hh, nullptr, N);
            sage_mfma<0, 0, 0><<<blocks, 512, 0, stream>>>(hh, rowptr, csr, W2l, b2, W2r, nullptr, out, N);
            return;
        }
    }

    // ---- fallback: round-5 CSR path (atomic rank; needs ~33 MB, proven) ----
    const int N4 = N / 4;
    const int NB = (N4 + 255) / 256;
    size_t off = 0;
    auto alloc = [&](size_t bytes) { size_t r = off; off += (bytes + 511) & ~(size_t)511; return r; };
    size_t f_counts = alloc((size_t)N * 4);
    size_t f_rowptr = alloc((size_t)(N + 1) * 4);
    size_t f_part   = alloc((size_t)NB * 4);
    size_t f_pscan  = alloc((size_t)NB * 4);
    size_t f_csr    = alloc((size_t)E * 4);
    size_t f_xh     = alloc((size_t)N * D * 2);
    size_t f_hh     = alloc((size_t)N * D * 2);

    int* counts  = (int*)((char*)d_ws + f_counts);
    int* rowptr  = (int*)((char*)d_ws + f_rowptr);
    int* partial = (int*)((char*)d_ws + f_part);
    int* pscan   = (int*)((char*)d_ws + f_pscan);
    int* csr     = (int*)((char*)d_ws + f_csr);
    f16* xh      = (f16*)((char*)d_ws + f_xh);
    f16* hh      = (f16*)((char*)d_ws + f_hh);
    int* rank    = (int*)hh;

    hipMemsetAsync(counts, 0, (size_t)N * 4, stream);
    count_rank_convert_kernel<<<2048, 256, 0, stream>>>(dst, counts, rank, E, x, xh, N * D / 4);
    scan_block_sums<<<NB, 256, 0, stream>>>(counts, partial, N4);
    scan_partials<<<1, 64, 0, stream>>>(partial, pscan, rowptr, NB, N, E);
    scan_final<<<NB, 256, 0, stream>>>(counts, pscan, rowptr, N4);
    fill_csr2<<<2048, 256, 0, stream>>>(src, dst, rowptr, rank, csr, E);

    sage_mfma<1, 1, 1><<<blocks, 512, 0, stream>>>(xh, rowptr, csr, W1l, b1, W1r, hh, nullptr, N);
    sage_mfma<0, 0, 1><<<blocks, 512, 0, stream>>>(hh, rowptr, csr, W2l, b2, W2r, nullptr, out, N);
}

// Round 13
// 161.574 us; speedup vs baseline: 1.8101x; 1.1083x over previous
//
#include <hip/hip_runtime.h>
#include <hip/hip_fp16.h>

#define D 64
#define IDXCAP 448    // per-wave LDS staged-index capacity (avg batch = 256)
#define NCH 512       // pass-1/2 chunks (grid)
#define MAXB 512      // max coarse buckets
#define RMAX 20       // p3 register-staged edges per thread

typedef _Float16 f16;
typedef _Float16 f16x8 __attribute__((ext_vector_type(8)));
typedef float f32x4 __attribute__((ext_vector_type(4)));

__device__ __forceinline__ float4 h4_to_f4(uint2 u) {
    float2 fa = __half22float2(__builtin_bit_cast(__half2, u.x));
    float2 fb = __half22float2(__builtin_bit_cast(__half2, u.y));
    return make_float4(fa.x, fa.y, fb.x, fb.y);
}

// ================= two-level histogram CSR build (zero global atomics) =================
// mat is bucket-major: mat[b * NCH + k]

__global__ __launch_bounds__(256) void p1_count_convert(
        const int* __restrict__ dst, int E, int chunk, int* __restrict__ mat, int bshift,
        const float* __restrict__ x, f16* __restrict__ xh, int n4) {
    __shared__ int h[MAXB];
    for (int i = threadIdx.x; i < MAXB; i += 256) h[i] = 0;
    __syncthreads();
    int k = blockIdx.x;
    int e0 = k * chunk;
    int e1 = min(E, e0 + chunk);
    for (int e = e0 + threadIdx.x; e < e1; e += 256)
        atomicAdd(&h[dst[e] >> bshift], 1);
    __syncthreads();
    for (int b = threadIdx.x; b < MAXB; b += 256)
        mat[b * NCH + k] = h[b];
    int t = blockIdx.x * 256 + threadIdx.x;
    int stride = gridDim.x * 256;
    for (int i = t; i < n4; i += stride) {
        float4 v = ((const float4*)x)[i];
        uint2 o;
        o.x = __builtin_bit_cast(unsigned int, __float22half2_rn(make_float2(v.x, v.y)));
        o.y = __builtin_bit_cast(unsigned int, __float22half2_rn(make_float2(v.z, v.w)));
        ((uint2*)xh)[i] = o;
    }
}

// per-bucket totals
__global__ __launch_bounds__(256) void scan_bt(const int* __restrict__ mat, int* __restrict__ tot) {
    __shared__ int sd[256];
    int b = blockIdx.x;
    int s = 0;
    for (int k = threadIdx.x; k < NCH; k += 256) s += mat[b * NCH + k];
    sd[threadIdx.x] = s; __syncthreads();
    for (int off = 128; off > 0; off >>= 1) {
        if (threadIdx.x < off) sd[threadIdx.x] += sd[threadIdx.x + off];
        __syncthreads();
    }
    if (threadIdx.x == 0) tot[b] = sd[0];
}

// merged: each bucket-block computes its own base (prefix over tot) + column scan
__global__ __launch_bounds__(512) void scan_col2(
        int* __restrict__ mat, const int* __restrict__ tot, int* __restrict__ bucketBase,
        int* __restrict__ rowptr, int nbuck, int N, int E) {
    __shared__ int sc[MAXB];
    int b = blockIdx.x;
    int t = threadIdx.x;
    int v = (t < nbuck) ? tot[t] : 0;
    sc[t] = v;
    __syncthreads();
    for (int off = 1; off < MAXB; off <<= 1) {
        int add = (t >= off) ? sc[t - off] : 0;
        __syncthreads();
        sc[t] += add;
        __syncthreads();
    }
    int base = sc[b] - tot[b];          // exclusive prefix at b
    if (t == 0) bucketBase[b] = base;
    if (b == 0 && t == 0) { bucketBase[nbuck] = E; rowptr[N] = E; }
    __syncthreads();
    // column scan over the NCH chunk-counts of bucket b (one element per thread)
    int l = mat[b * NCH + t];
    sc[t] = l;
    __syncthreads();
    for (int off = 1; off < MAXB; off <<= 1) {
        int add = (t >= off) ? sc[t - off] : 0;
        __syncthreads();
        sc[t] += add;
        __syncthreads();
    }
    mat[b * NCH + t] = base + sc[t] - l;
}

// packed scatter: pairs[pos] = (local_dst << 24) | src  (requires bshift<=8, N<2^24)
__global__ __launch_bounds__(256) void p2_scatter_p(
        const int* __restrict__ src, const int* __restrict__ dst, int E, int chunk,
        const int* __restrict__ mat, int bshift, unsigned int* __restrict__ pairs) {
    __shared__ int cur[MAXB];
    int k = blockIdx.x;
    for (int b = threadIdx.x; b < MAXB; b += 256)
        cur[b] = mat[b * NCH + k];
    __syncthreads();
    int e0 = k * chunk;
    int e1 = min(E, e0 + chunk);
    unsigned int lmask = (1u << bshift) - 1u;
    for (int e = e0 + threadIdx.x; e < e1; e += 256) {
        int d = dst[e], s = src[e];
        int pos = atomicAdd(&cur[d >> bshift], 1);   // LDS atomic only
        pairs[pos] = (((unsigned int)d & lmask) << 24) | (unsigned int)s;
    }
}

__global__ __launch_bounds__(256) void p3_build_p(
        const unsigned int* __restrict__ pairs, const int* __restrict__ bucketBase, int bshift,
        int* __restrict__ rowptr, int* __restrict__ csr, int N) {
    __shared__ int hist[1024];
    __shared__ int cur[1024];
    __shared__ int part[256];
    int b = blockIdx.x;
    int npb = 1 << bshift;
    int nb0 = b << bshift;
    int nn = min(N - nb0, npb);
    int e0 = bucketBase[b], e1 = bucketBase[b + 1];
    int cnt = e1 - e0;
    int t = threadIdx.x;
    for (int i = t; i < npb; i += 256) hist[i] = 0;
    __syncthreads();
    bool reg = (cnt <= 256 * RMAX);
    unsigned int v[RMAX];
    if (reg) {
        #pragma unroll
        for (int r = 0; r < RMAX; ++r) {
            int e = e0 + r * 256 + t;
            if (e < e1) {
                v[r] = pairs[e];
                atomicAdd(&hist[v[r] >> 24], 1);
            }
        }
    } else {
        for (int e = e0 + t; e < e1; e += 256)
            atomicAdd(&hist[pairs[e] >> 24], 1);
    }
    __syncthreads();
    int R = (nn + 255) >> 8;
    int base_i = t * R;
    int lsum = 0;
    for (int r = 0; r < R; ++r) { int i = base_i + r; if (i < nn) lsum += hist[i]; }
    part[t] = lsum;
    __syncthreads();
    for (int off = 1; off < 256; off <<= 1) {
        int add = (t >= off) ? part[t - off] : 0;
        __syncthreads();
        part[t] += add;
        __syncthreads();
    }
    int run = e0 + (part[t] - lsum);
    for (int r = 0; r < R; ++r) {
        int i = base_i + r;
        if (i < nn) {
            int hv = hist[i];
            rowptr[nb0 + i] = run;
            cur[i] = run;
            run += hv;
        }
    }
    __syncthreads();
    if (reg) {
        #pragma unroll
        for (int r = 0; r < RMAX; ++r) {
            int e = e0 + r * 256 + t;
            if (e < e1) {
                int pos = atomicAdd(&cur[v[r] >> 24], 1);    // LDS atomic only
                csr[pos] = (int)(v[r] & 0xFFFFFFu);
            }
        }
    } else {
        for (int e = e0 + t; e < e1; e += 256) {
            unsigned int p = pairs[e];
            int pos = atomicAdd(&cur[p >> 24], 1);
            csr[pos] = (int)(p & 0xFFFFFFu);
        }
    }
}

// unpacked variants (generality fallback when bshift>8 or N>=2^24)
__global__ __launch_bounds__(256) void p2_scatter(
        const int* __restrict__ src, const int* __restrict__ dst, int E, int chunk,
        const int* __restrict__ mat, int bshift, int2* __restrict__ pairs) {
    __shared__ int cur[MAXB];
    int k = blockIdx.x;
    for (int b = threadIdx.x; b < MAXB; b += 256)
        cur[b] = mat[b * NCH + k];
    __syncthreads();
    int e0 = k * chunk;
    int e1 = min(E, e0 + chunk);
    for (int e = e0 + threadIdx.x; e < e1; e += 256) {
        int d = dst[e], s = src[e];
        int pos = atomicAdd(&cur[d >> bshift], 1);
        pairs[pos] = make_int2(d, s);
    }
}

__global__ __launch_bounds__(256) void p3_build(
        const int2* __restrict__ pairs, const int* __restrict__ bucketBase, int bshift,
        int* __restrict__ rowptr, int* __restrict__ csr, int N) {
    __shared__ int hist[1024];
    __shared__ int cur[1024];
    __shared__ int part[256];
    int b = blockIdx.x;
    int npb = 1 << bshift;
    int nb0 = b << bshift;
    int nn = min(N - nb0, npb);
    int e0 = bucketBase[b], e1 = bucketBase[b + 1];
    int t = threadIdx.x;
    for (int i = t; i < npb; i += 256) hist[i] = 0;
    __syncthreads();
    for (int e = e0 + t; e < e1; e += 256)
        atomicAdd(&hist[pairs[e].x - nb0], 1);
    __syncthreads();
    int R = (nn + 255) >> 8;
    int base_i = t * R;
    int lsum = 0;
    for (int r = 0; r < R; ++r) { int i = base_i + r; if (i < nn) lsum += hist[i]; }
    part[t] = lsum;
    __syncthreads();
    for (int off = 1; off < 256; off <<= 1) {
        int add = (t >= off) ? part[t - off] : 0;
        __syncthreads();
        part[t] += add;
        __syncthreads();
    }
    int run = e0 + (part[t] - lsum);
    for (int r = 0; r < R; ++r) {
        int i = base_i + r;
        if (i < nn) {
            int hv = hist[i];
            rowptr[nb0 + i] = run;
            cur[i] = run;
            run += hv;
        }
    }
    __syncthreads();
    for (int e = e0 + t; e < e1; e += 256) {
        int2 p = pairs[e];
        int pos = atomicAdd(&cur[p.x - nb0], 1);
        csr[pos] = p.y;
    }
}

// ====================== fused SAGE layer (proven 57us config) ======================
#define GATHER_BODY(IP)                                                          \
    for (; j + 16 <= deg; j += 16) {                                             \
        int s0 = (IP)[j + r4];                                                   \
        int s1 = (IP)[j + 4 + r4];                                               \
        int s2 = (IP)[j + 8 + r4];                                               \
        int s3 = (IP)[j + 12 + r4];                                              \
        float4 g0 = h4_to_f4(xh2[(size_t)s0 * 16 + f8]);                         \
        float4 g1 = h4_to_f4(xh2[(size_t)s1 * 16 + f8]);                         \
        float4 g2 = h4_to_f4(xh2[(size_t)s2 * 16 + f8]);                         \
        float4 g3 = h4_to_f4(xh2[(size_t)s3 * 16 + f8]);                         \
        acc.x += (g0.x + g1.x) + (g2.x + g3.x);                                  \
        acc.y += (g0.y + g1.y) + (g2.y + g3.y);                                  \
        acc.z += (g0.z + g1.z) + (g2.z + g3.z);                                  \
        acc.w += (g0.w + g1.w) + (g2.w + g3.w);                                  \
    }                                                                            \
    if (j + 8 <= deg) {                                                          \
        int s0 = (IP)[j + r4];                                                   \
        int s1 = (IP)[j + 4 + r4];                                               \
        float4 g0 = h4_to_f4(xh2[(size_t)s0 * 16 + f8]);                         \
        float4 g1 = h4_to_f4(xh2[(size_t)s1 * 16 + f8]);                         \
        acc.x += g0.x + g1.x; acc.y += g0.y + g1.y;                              \
        acc.z += g0.z + g1.z; acc.w += g0.w + g1.w;                              \
        j += 8;                                                                  \
    }                                                                            \
    for (; j < deg; j += 4) {                                                    \
        int jj = j + r4;                                                         \
        if (jj < deg) {                                                          \
            float4 g = h4_to_f4(xh2[(size_t)(IP)[jj] * 16 + f8]);                \
            acc.x += g.x; acc.y += g.y; acc.z += g.z; acc.w += g.w;              \
        }                                                                        \
    }

template<int RELU, int OUT16>
__global__ __launch_bounds__(512, 4) void sage_mfma(
        const f16* __restrict__ xh, const int* __restrict__ rowptr,
        const int* __restrict__ csr,
        const float* __restrict__ Wl, const float* __restrict__ bias,
        const float* __restrict__ Wr,
        f16* __restrict__ out16, float* __restrict__ out32, int n_nodes) {
    __shared__ __align__(16) f16 sB[16 * 512];
    __shared__ __align__(16) f16 sA[8][16 * 72];
    __shared__ int sIdx[8][IDXCAP];

    for (int u = threadIdx.x; u < 16 * 64; u += blockDim.x) {
        int f = u >> 6;
        int l = u & 63;
        int t = f >> 2, q = f & 3;
        const float* Wsel = (q < 2) ? Wl : Wr;
        int d  = t * 16 + (l & 15);
        int k0 = (q & 1) * 32 + (l >> 4) * 8;
        const float4* wp = (const float4*)(Wsel + d * 64 + k0);
        float4 w0 = wp[0], w1 = wp[1];
        uint4 pk;
        pk.x = __builtin_bit_cast(unsigned int, __float22half2_rn(make_float2(w0.x, w0.y)));
        pk.y = __builtin_bit_cast(unsigned int, __float22half2_rn(make_float2(w0.z, w0.w)));
        pk.z = __builtin_bit_cast(unsigned int, __float22half2_rn(make_float2(w1.x, w1.y)));
        pk.w = __builtin_bit_cast(unsigned int, __float22half2_rn(make_float2(w1.z, w1.w)));
        *(uint4*)&sB[f * 512 + l * 8] = pk;
    }
    __syncthreads();

    const int lane = threadIdx.x & 63;
    const int wid  = threadIdx.x >> 6;
    const int r4   = lane >> 4;
    const int f8   = lane & 15;
    f16* myA = &sA[wid][0];
    int* myIdx = &sIdx[wid][0];

    float bias_t[4];
    #pragma unroll
    for (int t = 0; t < 4; ++t) bias_t[t] = bias[t * 16 + f8];

    const int wavesPerBlock = blockDim.x >> 6;
    const int gwave = blockIdx.x * wavesPerBlock + wid;
    const int nwaves = gridDim.x * wavesPerBlock;
    const uint2* __restrict__ xh2 = (const uint2*)xh;

    for (int nb = gwave * 16; nb < n_nodes; nb += nwaves * 16) {
        int rpl = 0;
        {
            int ii = nb + lane;
            if (lane < 17) rpl = rowptr[ii < n_nodes ? ii : n_nodes];
        }
        int rbase = __builtin_amdgcn_readlane(rpl, 0);
        int rend  = __builtin_amdgcn_readlane(rpl, 16);
        int cnt = rend - rbase;
        bool useLds = (cnt <= IDXCAP);

        if (useLds) {
            for (int c = lane; c < cnt; c += 64)
                myIdx[c] = csr[rbase + c];
        }

        int rn = nb + f8; if (rn >= n_nodes) rn = n_nodes - 1;
        const f16x8* rrow = (const f16x8*)(xh + (size_t)rn * 64);
        f16x8 a2 = rrow[r4];
        f16x8 a3 = rrow[4 + r4];

        #pragma unroll 1
        for (int i = 0; i < 16; ++i) {
            int r0 = __builtin_amdgcn_readlane(rpl, i);
            int r1 = __builtin_amdgcn_readlane(rpl, i + 1);
            int deg = r1 - r0;
            float4 acc = make_float4(0.f, 0.f, 0.f, 0.f);
            int j = 0;
            if (useLds) {
                const int* ip = myIdx + (r0 - rbase);
                GATHER_BODY(ip)
            } else {
                const int* ip = csr + r0;
                GATHER_BODY(ip)
            }
            acc.x += __shfl_xor(acc.x, 16, 64);
            acc.y += __shfl_xor(acc.y, 16, 64);
            acc.z += __shfl_xor(acc.z, 16, 64);
            acc.w += __shfl_xor(acc.w, 16, 64);
            acc.x += __shfl_xor(acc.x, 32, 64);
            acc.y += __shfl_xor(acc.y, 32, 64);
            acc.z += __shfl_xor(acc.z, 32, 64);
            acc.w += __shfl_xor(acc.w, 32, 64);
            float iv = 1.0f / (float)(deg > 0 ? deg : 1);
            if (r4 == (i & 3)) {
                uint2 w;
                w.x = __builtin_bit_cast(unsigned int,
                        __float22half2_rn(make_float2(acc.x * iv, acc.y * iv)));
                w.y = __builtin_bit_cast(unsigned int,
                        __float22half2_rn(make_float2(acc.z * iv, acc.w * iv)));
                *(uint2*)&myA[i * 72 + f8 * 4] = w;
            }
        }

        f16x8 a0 = *(const f16x8*)&myA[f8 * 72 + r4 * 8];
        f16x8 a1 = *(const f16x8*)&myA[f8 * 72 + 32 + r4 * 8];

        #pragma unroll
        for (int t = 0; t < 4; ++t) {
            f32x4 c = {0.f, 0.f, 0.f, 0.f};
            c = __builtin_amdgcn_mfma_f32_16x16x32_f16(a0, *(const f16x8*)&sB[(t*4+0)*512 + lane*8], c, 0, 0, 0);
            c = __builtin_amdgcn_mfma_f32_16x16x32_f16(a1, *(const f16x8*)&sB[(t*4+1)*512 + lane*8], c, 0, 0, 0);
            c = __builtin_amdgcn_mfma_f32_16x16x32_f16(a2, *(const f16x8*)&sB[(t*4+2)*512 + lane*8], c, 0, 0, 0);
            c = __builtin_amdgcn_mfma_f32_16x16x32_f16(a3, *(const f16x8*)&sB[(t*4+3)*512 + lane*8], c, 0, 0, 0);
            #pragma unroll
            for (int rr = 0; rr < 4; ++rr) {
                int n = nb + r4 * 4 + rr;
                if (n < n_nodes) {
                    float v = c[rr] + bias_t[t];
                    if (RELU) v = fmaxf(v, 0.f);
                    if (OUT16) out16[(size_t)n * 64 + t * 16 + f8] = (f16)v;
                    else       out32[(size_t)n * 64 + t * 16 + f8] = v;
                }
            }
        }
    }
}

// =================== fallback CSR build (round-5, atomic rank) ===================

__global__ void count_rank_convert_kernel(const int* __restrict__ dst, int* __restrict__ counts,
                                          int* __restrict__ rank, int E,
                                          const float* __restrict__ x, f16* __restrict__ xh, int n4) {
    int t = blockIdx.x * blockDim.x + threadIdx.x;
    int stride = gridDim.x * blockDim.x;
    int E4 = E >> 2;
    for (int e4 = t; e4 < E4; e4 += stride) {
        int4 d = ((const int4*)dst)[e4];
        int4 rk;
        rk.x = atomicAdd(&counts[d.x], 1);
        rk.y = atomicAdd(&counts[d.y], 1);
        rk.z = atomicAdd(&counts[d.z], 1);
        rk.w = atomicAdd(&counts[d.w], 1);
        ((int4*)rank)[e4] = rk;
    }
    for (int e = (E & ~3) + t; e < E; e += stride)
        rank[e] = atomicAdd(&counts[dst[e]], 1);
    for (int i = t; i < n4; i += stride) {
        float4 v = ((const float4*)x)[i];
        uint2 o;
        o.x = __builtin_bit_cast(unsigned int, __float22half2_rn(make_float2(v.x, v.y)));
        o.y = __builtin_bit_cast(unsigned int, __float22half2_rn(make_float2(v.z, v.w)));
        ((uint2*)xh)[i] = o;
    }
}

__global__ void scan_block_sums(const int* __restrict__ counts, int* __restrict__ partial, int N4) {
    __shared__ int sd[256];
    int idx = blockIdx.x * 256 + threadIdx.x;
    int s = 0;
    if (idx < N4) {
        int4 v = ((const int4*)counts)[idx];
        s = v.x + v.y + v.z + v.w;
    }
    sd[threadIdx.x] = s; __syncthreads();
    for (int off = 128; off > 0; off >>= 1) {
        if (threadIdx.x < off) sd[threadIdx.x] += sd[threadIdx.x + off];
        __syncthreads();
    }
    if (threadIdx.x == 0) partial[blockIdx.x] = sd[0];
}

__global__ void scan_partials(const int* __restrict__ partial, int* __restrict__ pscan,
                              int* __restrict__ rowptr, int NB, int N, int E) {
    if (threadIdx.x == 0 && blockIdx.x == 0) {
        int s = 0;
        for (int i = 0; i < NB; ++i) { pscan[i] = s; s += partial[i]; }
        rowptr[N] = E;
    }
}

__global__ void scan_final(const int* __restrict__ counts, const int* __restrict__ pscan,
                           int* __restrict__ rowptr, int N4) {
    __shared__ int sc[256];
    int idx = blockIdx.x * 256 + threadIdx.x;
    int4 v = make_int4(0, 0, 0, 0);
    if (idx < N4) v = ((const int4*)counts)[idx];
    int msum = v.x + v.y + v.z + v.w;
    sc[threadIdx.x] = msum; __syncthreads();
    for (int off = 1; off < 256; off <<= 1) {
        int add = (threadIdx.x >= (unsigned)off) ? sc[threadIdx.x - off] : 0;
        __syncthreads();
        sc[threadIdx.x] += add;
        __syncthreads();
    }
    int excl = sc[threadIdx.x] - msum + pscan[blockIdx.x];
    if (idx < N4) {
        int4 r;
        r.x = excl;
        r.y = excl + v.x;
        r.z = r.y + v.y;
        r.w = r.z + v.z;
        ((int4*)rowptr)[idx] = r;
    }
}

__global__ void fill_csr2(const int* __restrict__ src, const int* __restrict__ dst,
                          const int* __restrict__ rowptr, const int* __restrict__ rank,
                          int* __restrict__ csr, int E) {
    int t = blockIdx.x * blockDim.x + threadIdx.x;
    int stride = gridDim.x * blockDim.x;
    int E4 = E >> 2;
    for (int e4 = t; e4 < E4; e4 += stride) {
        int4 d = ((const int4*)dst)[e4];
        int4 rk = ((const int4*)rank)[e4];
        int4 s = ((const int4*)src)[e4];
        csr[rowptr[d.x] + rk.x] = s.x;
        csr[rowptr[d.y] + rk.y] = s.y;
        csr[rowptr[d.z] + rk.z] = s.z;
        csr[rowptr[d.w] + rk.w] = s.w;
    }
    for (int e = (E & ~3) + t; e < E; e += stride)
        csr[rowptr[dst[e]] + rank[e]] = src[e];
}

// ============================ launch ============================

extern "C" void kernel_launch(void* const* d_in, const int* in_sizes, int n_in,
                              void* d_out, int out_size, void* d_ws, size_t ws_size,
                              hipStream_t stream) {
    const float* x   = (const float*)d_in[0];
    const int*   ei  = (const int*)d_in[1];
    const float* W1l = (const float*)d_in[2];
    const float* b1  = (const float*)d_in[3];
    const float* W1r = (const float*)d_in[4];
    const float* W2l = (const float*)d_in[5];
    const float* b2  = (const float*)d_in[6];
    const float* W2r = (const float*)d_in[7];
    float* out = (float*)d_out;

    const int N = in_sizes[0] / D;   // 100000
    const int E = in_sizes[1] / 2;   // 1600000
    const int* src = ei;
    const int* dst = ei + E;

    int wavesNeeded = (N + 15) / 16;
    int blocks = (wavesNeeded + 7) / 8;       // 8 waves (512 threads) per block

    int bshift = 0;
    while ((1 << bshift) <= 1024 && ((N + (1 << bshift) - 1) >> bshift) > MAXB) ++bshift;
    bool bok = ((1 << bshift) <= 1024) && (((N + (1 << bshift) - 1) >> bshift) <= MAXB);
    int nbuck = bok ? ((N + (1 << bshift) - 1) >> bshift) : 0;
    bool packed = bok && (bshift <= 8) && (N < (1 << 24));

    // ---- preferred: histogram-partition CSR build ----
    {
        size_t off = 0;
        auto alloc = [&](size_t bytes) { size_t r = off; off += (bytes + 511) & ~(size_t)511; return r; };
        size_t o_mat    = alloc((size_t)MAXB * NCH * 4);
        size_t o_tot    = alloc((size_t)MAXB * 4);
        size_t o_bb     = alloc((size_t)(MAXB + 1) * 4);
        size_t o_pairs  = alloc((size_t)E * 8);          // superset (int2); packed uses half
        size_t o_rowptr = alloc((size_t)(N + 1) * 4);
        size_t o_csr    = alloc((size_t)E * 4);
        size_t o_xh     = alloc((size_t)N * D * 2);
        size_t o_hh     = alloc((size_t)N * D * 2);

        if (bok && E >= 1 && off <= ws_size) {
            int*  mat    = (int*)((char*)d_ws + o_mat);
            int*  tot    = (int*)((char*)d_ws + o_tot);
            int*  bb     = (int*)((char*)d_ws + o_bb);
            void* pairs  = (void*)((char*)d_ws + o_pairs);
            int*  rowptr = (int*)((char*)d_ws + o_rowptr);
            int*  csr    = (int*)((char*)d_ws + o_csr);
            f16*  xh     = (f16*)((char*)d_ws + o_xh);
            f16*  hh     = (f16*)((char*)d_ws + o_hh);

            int chunk = (E + NCH - 1) / NCH;
            p1_count_convert<<<NCH, 256, 0, stream>>>(dst, E, chunk, mat, bshift, x, xh, N * D / 4);
            scan_bt<<<nbuck, 256, 0, stream>>>(mat, tot);
            scan_col2<<<nbuck, 512, 0, stream>>>(mat, tot, bb, rowptr, nbuck, N, E);
            if (packed) {
                p2_scatter_p<<<NCH, 256, 0, stream>>>(src, dst, E, chunk, mat, bshift, (unsigned int*)pairs);
                p3_build_p<<<nbuck, 256, 0, stream>>>((const unsigned int*)pairs, bb, bshift, rowptr, csr, N);
            } else {
                p2_scatter<<<NCH, 256, 0, stream>>>(src, dst, E, chunk, mat, bshift, (int2*)pairs);
                p3_build<<<nbuck, 256, 0, stream>>>((const int2*)pairs, bb, bshift, rowptr, csr, N);
            }

            sage_mfma<1, 1><<<blocks, 512, 0, stream>>>(xh, rowptr, csr, W1l, b1, W1r, hh, nullptr, N);
            sage_mfma<0, 0><<<blocks, 512, 0, stream>>>(hh, rowptr, csr, W2l, b2, W2r, nullptr, out, N);
            return;
        }
    }

    // ---- fallback: round-5 CSR path (atomic rank; needs ~33 MB, proven) ----
    const int N4 = N / 4;
    const int NB = (N4 + 255) / 256;
    size_t off = 0;
    auto alloc = [&](size_t bytes) { size_t r = off; off += (bytes + 511) & ~(size_t)511; return r; };
    size_t f_counts = alloc((size_t)N * 4);
    size_t f_rowptr = alloc((size_t)(N + 1) * 4);
    size_t f_part   = alloc((size_t)NB * 4);
    size_t f_pscan  = alloc((size_t)NB * 4);
    size_t f_csr    = alloc((size_t)E * 4);
    size_t f_xh     = alloc((size_t)N * D * 2);
    size_t f_hh     = alloc((size_t)N * D * 2);

    int* counts  = (int*)((char*)d_ws + f_counts);
    int* rowptr  = (int*)((char*)d_ws + f_rowptr);
    int* partial = (int*)((char*)d_ws + f_part);
    int* pscan   = (int*)((char*)d_ws + f_pscan);
    int* csr     = (int*)((char*)d_ws + f_csr);
    f16* xh      = (f16*)((char*)d_ws + f_xh);
    f16* hh      = (f16*)((char*)d_ws + f_hh);
    int* rank    = (int*)hh;

    hipMemsetAsync(counts, 0, (size_t)N * 4, stream);
    count_rank_convert_kernel<<<2048, 256, 0, stream>>>(dst, counts, rank, E, x, xh, N * D / 4);
    scan_block_sums<<<NB, 256, 0, stream>>>(counts, partial, N4);
    scan_partials<<<1, 64, 0, stream>>>(partial, pscan, rowptr, NB, N, E);
    scan_final<<<NB, 256, 0, stream>>>(counts, pscan, rowptr, N4);
    fill_csr2<<<2048, 256, 0, stream>>>(src, dst, rowptr, rank, csr, E);

    sage_mfma<1, 1><<<blocks, 512, 0, stream>>>(xh, rowptr, csr, W1l, b1, W1r, hh, nullptr, N);
    sage_mfma<0, 0><<<blocks, 512, 0, stream>>>(hh, rowptr, csr, W2l, b2, W2r, nullptr, out, N);
}